// Round 6
// baseline (2551.171 us; speedup 1.0000x reference)
//
#include <hip/hip_runtime.h>
#include <math.h>

typedef unsigned short u16;
typedef __attribute__((ext_vector_type(8))) __bf16 bf16x8;
typedef __attribute__((ext_vector_type(4))) float f32x4;
typedef __attribute__((ext_vector_type(4))) _Float16 f16x4;

// ---------------- problem constants ----------------
#define MR   6144      // 48*128 rows (t-major: row = t*128 + bc)
#define KP1  320       // padded K for E=H=300
#define NPG  1280      // padded gate rows (1200 real, interleaved 4j+g)
#define NG   1200
#define WSEG 409600    // u16 elements per weight segment [1280][320]
// G fragment-major layout (f16 halves): addr = tt*163840 + s*20480 + T*256 + lane*4 (+r)
//   s = batch-slice (bc>>4), T = gate 16-tile (n>>4), lane = consumer lane, r = bc&3
#define GT_H 163840    // halves per timestep (8*80*256)
// U perm layout (u16): seg*409600 + (T*10 + kt)*512 + lane*8 (+e)
#define UPSEG 409600

// ---------------- workspace layout (byte offsets, 16B aligned) ----------------
#define OFF_ABF    0UL           // bf16 [6144][320]            3,932,160
#define OFF_WBF    3932160UL     // bf16 8 x [1280][320]        6,553,600 (eW,rW,dW,sW,eU,rU,dU,sU)
#define OFF_WCF    10485760UL    // f32  [300][1800] folded fc1 2,160,000
#define OFF_BIAS   12645760UL    // f32  4 x 1200 interleaved      19,200
#define OFF_GF     12664960UL    // f16  perm [48][8][80][64][4]  15,728,640
#define OFF_GR     28393600UL    // f16  perm                     15,728,640
#define OFF_HB     44122240UL    // bf16 2 dirs x [128][320]        163,840
#define OFF_ENC    44286080UL    // f32  [128][600]                 307,200
#define OFF_VB     44593280UL    // f32  8 x [64][600]            1,228,800
#define OFF_CO     45822080UL    // f32  8 x [64][300]              614,400
#define OFF_ATT    46436480UL    // f32  3 x 48*64 (AMX,AMN,SS)      36,864
#define OFF_PT     46473344UL    // f32  [2400][64] pooled^T        614,400
#define OFF_LG     47087744UL    // f32  64*300                      76,800
#define OFF_UP     47164544UL    // bf16 4 x Uperm [80][10][64][8] 3,276,800

__device__ __forceinline__ float sigf(float x) { return 1.0f / (1.0f + expf(-x)); }
__device__ __forceinline__ float fsig(float x) { return 1.0f / (1.0f + __expf(-x)); }
__device__ __forceinline__ float ftanh(float x) { return 1.0f - 2.0f / (__expf(2.0f * x) + 1.0f); }

__device__ __forceinline__ u16 f2bf(float x) {
    union { float f; unsigned int u; } v; v.f = x;
    unsigned int r = v.u + 0x7fffu + ((v.u >> 16) & 1u);   // RNE
    return (u16)(r >> 16);
}
__device__ __forceinline__ float bf2f(u16 x) {
    union { unsigned int u; float f; } v; v.u = ((unsigned int)x) << 16; return v.f;
}

__device__ __forceinline__ void gld_lds16(const u16* g, u16* l) {
    __builtin_amdgcn_global_load_lds(
        (const __attribute__((address_space(1))) unsigned int*)g,
        (__attribute__((address_space(3))) unsigned int*)l, 16, 0, 0);
}

// ---------------- embedding gather -> bf16, K zero-padded ----------------
__global__ __launch_bounds__(256) void gather_bf(const int* __restrict__ x1,
                                                 const int* __restrict__ x2,
                                                 const float* __restrict__ emb,
                                                 u16* __restrict__ abf) {
    int idx = blockIdx.x * 256 + threadIdx.x;
    if (idx >= MR * KP1) return;
    int r = idx / KP1, k = idx % KP1;
    float v = 0.0f;
    if (k < 300) {
        int t = r >> 7, bc = r & 127;
        int tok = (bc < 64) ? x1[t * 64 + bc] : x2[t * 64 + bc - 64];
        v = emb[tok * 300 + k];
    }
    abf[idx] = f2bf(v);
}

// ---------------- 8 weight matrices [1200][300] -> gate-interleaved bf16 [1280][320] ----------------
__global__ __launch_bounds__(256) void wconv8_k(const float* __restrict__ w0, const float* __restrict__ w1,
                                                const float* __restrict__ w2, const float* __restrict__ w3,
                                                const float* __restrict__ w4, const float* __restrict__ w5,
                                                const float* __restrict__ w6, const float* __restrict__ w7,
                                                u16* __restrict__ out) {
    int idx = blockIdx.x * 256 + threadIdx.x;
    if (idx >= 8 * NPG * KP1) return;
    int s = idx / (NPG * KP1), rem = idx % (NPG * KP1);
    int r = rem / KP1, k = rem % KP1;
    const float* w = (s == 0) ? w0 : (s == 1) ? w1 : (s == 2) ? w2 : (s == 3) ? w3
                   : (s == 4) ? w4 : (s == 5) ? w5 : (s == 6) ? w6 : w7;
    float v = 0.0f;
    if (r < NG && k < 300) {
        int j = r >> 2, g = r & 3;           // interleaved row 4j+g <- source row g*300+j
        v = w[(g * 300 + j) * 300 + k];
    }
    out[idx] = f2bf(v);
}

// ---------------- U segs -> B-fragment-major perm: UP[seg][T][kt][lane][8] ----------------
__global__ __launch_bounds__(256) void uperm_k(const u16* __restrict__ WU,
                                               u16* __restrict__ UP) {
    int idx = blockIdx.x * 256 + threadIdx.x;
    if (idx >= 4 * UPSEG) return;
    int seg = idx / UPSEG, pos = idx % UPSEG;
    int T = pos / 5120, kt = (pos / 512) % 10, l = (pos >> 3) & 63, e = pos & 7;
    int n = T * 16 + (l & 15);
    int k = kt * 32 + (l >> 4) * 8 + e;
    UP[idx] = WU[(size_t)seg * WSEG + (size_t)n * KP1 + k];
}

// ---------------- 4 bias pairs -> interleaved f32 [4][1200] ----------------
__global__ __launch_bounds__(256) void bconv_k(const float* __restrict__ b0i, const float* __restrict__ b0h,
                                               const float* __restrict__ b1i, const float* __restrict__ b1h,
                                               const float* __restrict__ b2i, const float* __restrict__ b2h,
                                               const float* __restrict__ b3i, const float* __restrict__ b3h,
                                               float* __restrict__ out) {
    int idx = blockIdx.x * 256 + threadIdx.x;
    if (idx >= 4 * NG) return;
    int s = idx / NG, n = idx % NG;
    int j = n >> 2, g = n & 3;
    int src = g * 300 + j;
    const float* bi = (s == 0) ? b0i : (s == 1) ? b1i : (s == 2) ? b2i : b3i;
    const float* bh = (s == 0) ? b0h : (s == 1) ? b1h : (s == 2) ? b2h : b3h;
    out[idx] = bi[src] + bh[src];
}

// ---------------- folded fc1 weight (fp32) [300][1800] ----------------
__global__ __launch_bounds__(256) void wcat_k(const float* __restrict__ f1w,
                                              float* __restrict__ wc) {
    int idx = blockIdx.x * 256 + threadIdx.x;
    if (idx >= 300 * 1800) return;
    int n = idx / 1800, k = idx % 1800;
    int nk = n * 2400 + k;
    float v;
    if (k < 600)       v = f1w[nk] + f1w[nk + 1800];   // c coeff: W1+W4
    else if (k < 1200) v = f1w[nk] - f1w[nk + 1200];   // a coeff: W2-W4
    else               v = f1w[nk];                    // c*a coeff: W3
    wc[idx] = v;
}

// ---------------- bf16 MFMA GEMM -> G in consumer-fragment-major f16 layout ----------------
// grid (48, 10): tile (tt, nt). Producer lane == consumer lane (derived identity):
// frag (i,j), regs r=0..3 -> Gh[tt*GT_H + (wm*4+i)*20480 + (nt*8+wn*4+j)*256 + ln*4 + r]
__global__ __launch_bounds__(256) void gemm_bt(const u16* __restrict__ A,
                                               const u16* __restrict__ B,
                                               const float* __restrict__ bias,
                                               _Float16* __restrict__ Gh) {
    __shared__ __align__(16) u16 smA[128 * 32];
    __shared__ __align__(16) u16 smB[128 * 32];
    int m0 = blockIdx.x * 128, n0 = blockIdx.y * 128;
    int tid = threadIdx.x, ln = tid & 63;
    int wm = (tid >> 6) & 1, wn = tid >> 7;
    int lrow = ln & 15, lq = ln >> 4;
    f32x4 acc[4][4] = {};
    for (int k0 = 0; k0 < KP1; k0 += 32) {
#pragma unroll
        for (int p = 0; p < 2; p++) {
            int e = (p * 256 + tid) * 8;
            int r = e >> 5, kk = e & 31;
            gld_lds16(A + (size_t)(m0 + r) * KP1 + k0 + kk, smA + e);
            gld_lds16(B + (size_t)(n0 + r) * KP1 + k0 + kk, smB + e);
        }
        __syncthreads();
        bf16x8 av[4], bv[4];
#pragma unroll
        for (int i = 0; i < 4; i++) {
            av[i] = *(const bf16x8*)&smA[(wm * 64 + i * 16 + lrow) * 32 + lq * 8];
            bv[i] = *(const bf16x8*)&smB[(wn * 64 + i * 16 + lrow) * 32 + lq * 8];
        }
#pragma unroll
        for (int i = 0; i < 4; i++)
#pragma unroll
            for (int j = 0; j < 4; j++)
                acc[i][j] = __builtin_amdgcn_mfma_f32_16x16x32_bf16(av[i], bv[j], acc[i][j], 0, 0, 0);
        __syncthreads();
    }
    size_t tb = (size_t)blockIdx.x * GT_H;
#pragma unroll
    for (int i = 0; i < 4; i++) {
        int s = wm * 4 + i;
#pragma unroll
        for (int j = 0; j < 4; j++) {
            int n = n0 + wn * 64 + j * 16 + lrow;
            int Tg = (n0 >> 4) + wn * 4 + j;
            f16x4 v;
            if (n < NG) {
                float bb = bias[n];
#pragma unroll
                for (int r = 0; r < 4; r++) v[r] = (_Float16)(acc[i][j][r] + bb);
            } else {
                v = (f16x4)0;
            }
            *(f16x4*)(Gh + tb + (size_t)s * 20480 + (size_t)Tg * 256 + (size_t)ln * 4) = v;
        }
    }
}

// ---------------- batch-partitioned MFMA LSTM: 48 steps, no inter-block sync ----------------
// grid (8 batch-slices, 2 dirs), block 256 = 4 waves. h in LDS (double-buffered),
// c in VGPRs, U streamed from L2 (fragment-major), G streamed (fragment-major, prefetched).
__global__ __launch_bounds__(256, 1) void lstm_batch(const _Float16* __restrict__ Gf,
                                                     const _Float16* __restrict__ Gr,
                                                     const u16* __restrict__ Upf,
                                                     const u16* __restrict__ Upr,
                                                     u16* __restrict__ hb) {
    int dir = blockIdx.y, s = blockIdx.x;
    const _Float16* G = dir ? Gr : Gf;
    const u16* Up = dir ? Upr : Upf;
    u16* hgout = hb + (size_t)dir * 40960 + (size_t)s * 16 * KP1;

    int tid = threadIdx.x, ln = tid & 63, w = tid >> 6;
    int lrow = ln & 15, lq = ln >> 4;

    __shared__ float P[16][1284];          // gate staging, padded stride
    __shared__ __align__(16) u16 h2[2][16 * 328];   // h double buffer, padded stride 328

    for (int i = tid; i < 2 * 16 * 328; i += 256) ((u16*)h2)[i] = 0;
    __syncthreads();

    int jset = tid & 15, brow = tid >> 4;
    float c[20];
#pragma unroll
    for (int q = 0; q < 20; q++) c[q] = 0.0f;

    const _Float16* Gs = G + ((size_t)s * 80 + w * 20) * 256 + (size_t)ln * 4;
    f16x4 gpre[20];
    {
        int ttg = dir ? 47 : 0;
        const _Float16* Gt = Gs + (size_t)ttg * GT_H;
#pragma unroll
        for (int T = 0; T < 20; T++) gpre[T] = *(const f16x4*)(Gt + (size_t)T * 256);
    }

    for (int t = 0; t < 48; t++) {
        const u16* hin = h2[t & 1];
        u16* hout = h2[(t + 1) & 1];

        // A-fragments from LDS h (conflict-free via 328 stride)
        bf16x8 av[10];
#pragma unroll
        for (int kt = 0; kt < 10; kt++)
            av[kt] = *(const bf16x8*)&hin[lrow * 328 + kt * 32 + lq * 8];

        // acc initialized from G (bias pre-added by producer)
        f32x4 acc[20];
#pragma unroll
        for (int T = 0; T < 20; T++) {
            f32x4 a;
#pragma unroll
            for (int r = 0; r < 4; r++) a[r] = (float)gpre[T][r];
            acc[T] = a;
        }

        // U stream: kt-outer, T-inner (independent MFMAs, load/compute overlap)
#pragma unroll
        for (int kt = 0; kt < 10; kt++) {
            bf16x8 bv[20];
#pragma unroll
            for (int T = 0; T < 20; T++)
                bv[T] = *(const bf16x8*)(Up + (((size_t)(w * 20 + T) * 10 + kt) * 64 + ln) * 8);
#pragma unroll
            for (int T = 0; T < 20; T++)
                acc[T] = __builtin_amdgcn_mfma_f32_16x16x32_bf16(av[kt], bv[T], acc[T], 0, 0, 0);
        }

        // stage gates to LDS (C-frag: col = n-tile col, rows = lq*4+r)
#pragma unroll
        for (int T = 0; T < 20; T++) {
            int ncol = (w * 20 + T) * 16 + lrow;
#pragma unroll
            for (int r = 0; r < 4; r++)
                P[lq * 4 + r][ncol] = acc[T][r];
        }
        __syncthreads();

        // prefetch next step's G (independent of h; overlaps nonlinearity)
        if (t < 47) {
            int ttg = dir ? 46 - t : t + 1;
            const _Float16* Gt = Gs + (size_t)ttg * GT_H;
#pragma unroll
            for (int T = 0; T < 20; T++) gpre[T] = *(const f16x4*)(Gt + (size_t)T * 256);
        }

        // gate nonlinearity: thread owns (brow, jset+16q), c in regs
#pragma unroll
        for (int q = 0; q < 20; q++) {
            int j = jset + q * 16;
            if (j < 300) {
                f32x4 gv = *(const f32x4*)&P[brow][4 * j];    // i,f,g,o
                float cn = fsig(gv[1]) * c[q] + fsig(gv[0]) * ftanh(gv[2]);
                float hn = fsig(gv[3]) * ftanh(cn);
                c[q] = cn;
                hout[brow * 328 + j] = f2bf(hn);
                if (t == 47) hgout[(size_t)brow * KP1 + j] = f2bf(hn);
            }
        }
        __syncthreads();
    }
}

// ---------------- final-h concat (batch-reversal quirk): [128][600] f32 ----------------
__global__ __launch_bounds__(256) void enc_k(const u16* __restrict__ hF,
                                             const u16* __restrict__ hR,
                                             float* __restrict__ enc) {
    int idx = blockIdx.x * 256 + threadIdx.x;
    if (idx >= 128 * 600) return;
    int bc = idx / 600, d = idx % 600;
    int seq = bc >> 6, b = bc & 63;
    enc[idx] = (d < 300) ? bf2f(hF[bc * KP1 + d])
                         : bf2f(hR[(seq * 64 + 63 - b) * KP1 + d - 300]);
}

// ---------------- build 8 coefficient vectors V[8][64][600] ----------------
__global__ __launch_bounds__(256) void vbuf_k(const float* __restrict__ enc,
                                              float* __restrict__ V) {
    int idx = blockIdx.x * 256 + threadIdx.x;
    if (idx >= 64 * 600) return;
    int b = idx / 600, d = idx % 600;
    float e1 = enc[b * 600 + d], e2 = enc[(64 + b) * 600 + d];
    float p = fmaxf(e2, 0.0f), nn = fminf(e2, 0.0f);
    V[0 * 38400 + idx] = e1;
    V[1 * 38400 + idx] = p;
    V[2 * 38400 + idx] = nn;
    V[3 * 38400 + idx] = e1 * p;
    V[4 * 38400 + idx] = e1 * nn;
    V[5 * 38400 + idx] = e2;
    V[6 * 38400 + idx] = e1;
    V[7 * 38400 + idx] = e1 * e2;
}

// ---------------- attention scalars (rank-1 collapse): AMX/AMN/SS [48][64] ----------------
__global__ __launch_bounds__(256) void attn_lite(const float* __restrict__ enc,
                                                 const float* __restrict__ x1m,
                                                 const float* __restrict__ x2m,
                                                 float* __restrict__ AMX,
                                                 float* __restrict__ AMN,
                                                 float* __restrict__ SS) {
    int b = blockIdx.x, tid = threadIdx.x;
    __shared__ float sc[48][49];
    __shared__ float rmx[4], rmn[4];
    __shared__ float MxMn[2];
    float mx = -3.4e38f, mn = 3.4e38f;
    for (int d = tid; d < 600; d += 256) {
        float p = enc[b * 600 + d] * enc[(64 + b) * 600 + d];
        mx = fmaxf(mx, p); mn = fminf(mn, p);
    }
    for (int off = 32; off; off >>= 1) {
        mx = fmaxf(mx, __shfl_down(mx, off));
        mn = fminf(mn, __shfl_down(mn, off));
    }
    if ((tid & 63) == 0) { rmx[tid >> 6] = mx; rmn[tid >> 6] = mn; }
    __syncthreads();
    if (tid == 0) {
        MxMn[0] = fmaxf(fmaxf(rmx[0], rmx[1]), fmaxf(rmx[2], rmx[3]));
        MxMn[1] = fminf(fminf(rmn[0], rmn[1]), fminf(rmn[2], rmn[3]));
    }
    __syncthreads();
    float Mx = MxMn[0], Mn = MxMn[1];
    for (int idx = tid; idx < 2304; idx += 256) {
        int i = idx / 48, j = idx % 48;
        float q = x1m[i * 64 + b] * x2m[j * 64 + b];
        sc[i][j] = (q > 0.0f) ? q * Mx : ((q < 0.0f) ? q * Mn : 0.0f);
    }
    __syncthreads();
    if (tid < 48) {                       // alpha over axis j, row i = tid
        int i = tid;
        float m = -3.4e38f;
        for (int j = 0; j < 48; j++) m = fmaxf(m, sc[i][j]);
        float sum = 0.0f;
        for (int j = 0; j < 48; j++) sum += expf(sc[i][j] - m) * x2m[j * 64 + b];
        float wmax = -3.4e38f, wmin = 3.4e38f;
        for (int j = 0; j < 48; j++) {
            float w = expf(sc[i][j] - m) * x2m[j * 64 + b] * x2m[j * 64 + b];
            wmax = fmaxf(wmax, w); wmin = fminf(wmin, w);
        }
        AMX[i * 64 + b] = wmax / sum;
        AMN[i * 64 + b] = wmin / sum;
    } else if (tid >= 64 && tid < 112) {  // beta over axis i, col j = tid-64
        int j = tid - 64;
        float m = -3.4e38f;
        for (int i = 0; i < 48; i++) m = fmaxf(m, sc[i][j]);
        float sum = 0.0f, sm = 0.0f;
        for (int i = 0; i < 48; i++) {
            float e = expf(sc[i][j] - m) * x1m[i * 64 + b];
            sum += e; sm += e * x1m[i * 64 + b];
        }
        SS[j * 64 + b] = sm / sum;
    }
}

// ---------------- 8 small fp32 GEMMs: CO[s][64][300] = V[s] @ WcSlice^T ----------------
__global__ __launch_bounds__(256) void coeff_gemm(const float* __restrict__ V,
                                                  const float* __restrict__ Wc,
                                                  float* __restrict__ CO) {
    __shared__ float As[16][64];
    __shared__ float Ws[16][64];
    int s = blockIdx.y;
    const int offs[8] = {0, 600, 600, 1200, 1200, 0, 600, 1200};
    int koff = offs[s];
    const float* A = V + (size_t)s * 38400;
    float* C = CO + (size_t)s * 19200;
    int n0 = blockIdx.x * 64;
    int tid = threadIdx.x;
    int lrow = tid >> 2;
    int lk4 = (tid & 3) << 2;
    int tm = (tid & 15) << 2;
    int tn = (tid >> 4) << 2;
    int nW = n0 + lrow;
    float acc[4][4] = {};
    for (int k0 = 0; k0 < 600; k0 += 16) {
        __syncthreads();
#pragma unroll
        for (int q = 0; q < 4; q++) {
            int k = k0 + lk4 + q;
            As[lk4 + q][lrow] = (k < 600) ? A[lrow * 600 + k] : 0.0f;
            Ws[lk4 + q][lrow] = (k < 600 && nW < 300) ? Wc[(size_t)nW * 1800 + koff + k] : 0.0f;
        }
        __syncthreads();
#pragma unroll
        for (int kk = 0; kk < 16; kk++) {
            float a0 = As[kk][tm], a1 = As[kk][tm + 1], a2 = As[kk][tm + 2], a3 = As[kk][tm + 3];
            float w0 = Ws[kk][tn], w1 = Ws[kk][tn + 1], w2 = Ws[kk][tn + 2], w3 = Ws[kk][tn + 3];
            acc[0][0] += a0 * w0; acc[0][1] += a0 * w1; acc[0][2] += a0 * w2; acc[0][3] += a0 * w3;
            acc[1][0] += a1 * w0; acc[1][1] += a1 * w1; acc[1][2] += a1 * w2; acc[1][3] += a1 * w3;
            acc[2][0] += a2 * w0; acc[2][1] += a2 * w1; acc[2][2] += a2 * w2; acc[2][3] += a2 * w3;
            acc[3][0] += a3 * w0; acc[3][1] += a3 * w1; acc[3][2] += a3 * w2; acc[3][3] += a3 * w3;
        }
    }
#pragma unroll
    for (int ii = 0; ii < 4; ii++) {
        int m = tm + ii;
#pragma unroll
        for (int jn = 0; jn < 4; jn++) {
            int n = n0 + tn + jn;
            if (n < 300) C[m * 300 + n] = acc[ii][jn];
        }
    }
}

// ---------------- rank-combine + relu -> bf16 h1 (t-major [6144][320]) ----------------
__global__ __launch_bounds__(320) void combine_k(const float* __restrict__ CO,
                                                 const float* __restrict__ f1b,
                                                 const float* __restrict__ x1m,
                                                 const float* __restrict__ x2m,
                                                 const float* __restrict__ AMX,
                                                 const float* __restrict__ AMN,
                                                 const float* __restrict__ SS,
                                                 u16* __restrict__ OUT) {
    int r = blockIdx.x;
    int t = r >> 7, bc = r & 127;
    int seq = bc >> 6, b = bc & 63;
    int n = threadIdx.x;
    if (n >= 300) return;
    int bn = b * 300 + n;
    float pre;
    if (seq == 0) {
        float m1 = x1m[t * 64 + b], am = AMX[t * 64 + b], an = AMN[t * 64 + b];
        pre = m1 * CO[bn] + am * CO[19200 + bn] + an * CO[2 * 19200 + bn]
            + m1 * am * CO[3 * 19200 + bn] + m1 * an * CO[4 * 19200 + bn] + f1b[n];
    } else {
        float m2 = x2m[t * 64 + b], sv = SS[t * 64 + b];
        pre = m2 * CO[5 * 19200 + bn] + sv * CO[6 * 19200 + bn]
            + m2 * sv * CO[7 * 19200 + bn] + f1b[n];
    }
    OUT[(size_t)r * KP1 + n] = f2bf(fmaxf(pre, 0.0f));
}

// ---------------- masked mean/max pooling -> pooled^T [2400][64] ----------------
__global__ __launch_bounds__(256) void pool_k(const float* __restrict__ dctx,
                                              const float* __restrict__ x1m,
                                              const float* __restrict__ x2m,
                                              float* __restrict__ pooledT) {
    int idx = blockIdx.x * 256 + threadIdx.x;
    if (idx >= 64 * 2400) return;
    int b = idx / 2400, col = idx % 2400;
    int sec = col / 600, d = col % 600;
    const float* msk = (sec < 2) ? x1m : x2m;
    float v = dctx[((sec < 2 ? 0 : 64) + b) * 600 + d];
    float out;
    if ((sec & 1) == 0) {
        float s = 0, sm = 0;
        for (int t = 0; t < 48; t++) { float mv = msk[t * 64 + b]; s += v * mv; sm += mv; }
        out = s / sm;
    } else {
        float m = -3.4e38f;
        for (int t = 0; t < 48; t++) m = fmaxf(m, v * msk[t * 64 + b]);
        out = m;
    }
    pooledT[col * 64 + b] = out;
}

// ---------------- fc2 + tanh (k-parallel, coalesced pooled^T) ----------------
__global__ __launch_bounds__(256) void fc2_k2(const float* __restrict__ pooledT,
                                              const float* __restrict__ f2w,
                                              const float* __restrict__ f2b,
                                              float* __restrict__ logit) {
    __shared__ float wl[2400];
    __shared__ float red[256];
    int n = blockIdx.x;
    for (int i = threadIdx.x; i < 2400; i += 256) wl[i] = f2w[n * 2400 + i];
    __syncthreads();
    int b = threadIdx.x & 63, kc = threadIdx.x >> 6;
    float acc = 0.0f;
    int k0 = kc * 600;
    for (int kk = 0; kk < 600; kk++) acc += pooledT[(k0 + kk) * 64 + b] * wl[k0 + kk];
    red[threadIdx.x] = acc;
    __syncthreads();
    if (threadIdx.x < 64) {
        float s = red[b] + red[64 + b] + red[128 + b] + red[192 + b];
        logit[b * 300 + n] = tanhf(s + f2b[n]);
    }
}

// ---------------- output layer (wave-reduced) ----------------
__global__ __launch_bounds__(64) void out_k2(const float* __restrict__ logit,
                                             const float* __restrict__ fow,
                                             const float* __restrict__ fob,
                                             float* __restrict__ out) {
    int b = blockIdx.x, tid = threadIdx.x;
    float p0 = 0, p1 = 0, p2 = 0;
    for (int k = tid; k < 300; k += 64) {
        float l = logit[b * 300 + k];
        p0 += l * fow[k]; p1 += l * fow[300 + k]; p2 += l * fow[600 + k];
    }
    for (int off = 32; off; off >>= 1) {
        p0 += __shfl_down(p0, off);
        p1 += __shfl_down(p1, off);
        p2 += __shfl_down(p2, off);
    }
    if (tid == 0) {
        out[b * 3 + 0] = p0 + fob[0];
        out[b * 3 + 1] = p1 + fob[1];
        out[b * 3 + 2] = p2 + fob[2];
    }
}

extern "C" void kernel_launch(void* const* d_in, const int* in_sizes, int n_in,
                              void* d_out, int out_size, void* d_ws, size_t ws_size,
                              hipStream_t stream) {
    (void)in_sizes; (void)n_in; (void)out_size; (void)ws_size;
    const int*   x1  = (const int*)d_in[0];
    const float* x1m = (const float*)d_in[1];
    const int*   x2  = (const int*)d_in[2];
    const float* x2m = (const float*)d_in[3];
    const float* emb = (const float*)d_in[5];
    const float* eW  = (const float*)d_in[6];
    const float* ebi = (const float*)d_in[8];
    const float* ebh = (const float*)d_in[9];
    const float* rW  = (const float*)d_in[10];
    const float* rbi = (const float*)d_in[12];
    const float* rbh = (const float*)d_in[13];
    const float* dW  = (const float*)d_in[14];
    const float* dbi = (const float*)d_in[16];
    const float* dbh = (const float*)d_in[17];
    const float* sW  = (const float*)d_in[18];
    const float* sbi = (const float*)d_in[20];
    const float* sbh = (const float*)d_in[21];
    const float* eU  = (const float*)d_in[7];
    const float* rU  = (const float*)d_in[11];
    const float* dU  = (const float*)d_in[15];
    const float* sU  = (const float*)d_in[19];
    const float* f1w = (const float*)d_in[22];
    const float* f1b = (const float*)d_in[23];
    const float* f2w = (const float*)d_in[24];
    const float* f2b = (const float*)d_in[25];
    const float* fow = (const float*)d_in[26];
    const float* fob = (const float*)d_in[27];

    char* wsb = (char*)d_ws;
    u16*       ABF  = (u16*)(wsb + OFF_ABF);
    u16*       WBF  = (u16*)(wsb + OFF_WBF);
    float*     WCF  = (float*)(wsb + OFF_WCF);
    float*     BIAS = (float*)(wsb + OFF_BIAS);
    _Float16*  GFh  = (_Float16*)(wsb + OFF_GF);
    _Float16*  GRh  = (_Float16*)(wsb + OFF_GR);
    u16*       HB   = (u16*)(wsb + OFF_HB);
    float*     ENC  = (float*)(wsb + OFF_ENC);
    float*     VB   = (float*)(wsb + OFF_VB);
    float*     CO   = (float*)(wsb + OFF_CO);
    float*     AMX  = (float*)(wsb + OFF_ATT);
    float*     AMN  = AMX + 3072;
    float*     SS   = AMX + 6144;
    float*     PT   = (float*)(wsb + OFF_PT);
    float*     LG   = (float*)(wsb + OFF_LG);
    u16*       UP   = (u16*)(wsb + OFF_UP);

    u16* HF0 = HB;
    u16* HR0 = HB + 40960;

    // ---- conversions ----
    gather_bf<<<dim3((MR * KP1 + 255) / 256), 256, 0, stream>>>(x1, x2, emb, ABF);
    wconv8_k<<<dim3((8 * NPG * KP1 + 255) / 256), 256, 0, stream>>>(eW, rW, dW, sW, eU, rU, dU, sU, WBF);
    uperm_k<<<dim3((4 * UPSEG + 255) / 256), 256, 0, stream>>>(WBF + 4 * WSEG, UP);
    bconv_k<<<dim3((4 * NG + 255) / 256), 256, 0, stream>>>(ebi, ebh, rbi, rbh, dbi, dbh, sbi, sbh, BIAS);
    wcat_k<<<dim3((300 * 1800 + 255) / 256), 256, 0, stream>>>(f1w, WCF);

    // ---- encoder ----
    gemm_bt<<<dim3(48, 10), 256, 0, stream>>>(ABF, WBF,        BIAS,      GFh);
    gemm_bt<<<dim3(48, 10), 256, 0, stream>>>(ABF, WBF + WSEG, BIAS + NG, GRh);
    lstm_batch<<<dim3(8, 2), 256, 0, stream>>>(GFh, GRh, UP, UP + UPSEG, HB);

    // ---- attention (rank-1 collapse) + fc1 ----
    enc_k<<<dim3((128 * 600 + 255) / 256), 256, 0, stream>>>(HF0, HR0, ENC);
    vbuf_k<<<dim3((64 * 600 + 255) / 256), 256, 0, stream>>>(ENC, VB);
    attn_lite<<<dim3(64), 256, 0, stream>>>(ENC, x1m, x2m, AMX, AMN, SS);
    coeff_gemm<<<dim3(5, 8), 256, 0, stream>>>(VB, WCF, CO);
    combine_k<<<dim3(6144), 320, 0, stream>>>(CO, f1b, x1m, x2m, AMX, AMN, SS, ABF);

    // ---- decoder ----
    gemm_bt<<<dim3(48, 10), 256, 0, stream>>>(ABF, WBF + 2 * WSEG, BIAS + 2 * NG, GFh);
    gemm_bt<<<dim3(48, 10), 256, 0, stream>>>(ABF, WBF + 3 * WSEG, BIAS + 3 * NG, GRh);
    lstm_batch<<<dim3(8, 2), 256, 0, stream>>>(GFh, GRh, UP + 2 * UPSEG, UP + 3 * UPSEG, HB);

    // ---- pooling + classifier ----
    enc_k<<<dim3((128 * 600 + 255) / 256), 256, 0, stream>>>(HF0, HR0, ENC);
    pool_k<<<dim3((64 * 2400 + 255) / 256), 256, 0, stream>>>(ENC, x1m, x2m, PT);
    fc2_k2<<<dim3(300), 256, 0, stream>>>(PT, f2w, f2b, LG);
    out_k2<<<dim3(64), 64, 0, stream>>>(LG, fow, fob, (float*)d_out);
}

// Round 7
// 1046.048 us; speedup vs baseline: 2.4389x; 2.4389x over previous
//
#include <hip/hip_runtime.h>
#include <math.h>

typedef unsigned short u16;
typedef unsigned int u32;
typedef unsigned long long u64;
typedef __attribute__((ext_vector_type(8))) __bf16 bf16x8;
typedef __attribute__((ext_vector_type(4))) float f32x4;
typedef __attribute__((ext_vector_type(4))) _Float16 f16x4;

// ---------------- problem constants ----------------
#define MR   6144      // 48*128 rows (t-major: row = t*128 + bc)
#define KP1  320       // padded K for E=H=300
#define NPG  1280      // padded gate rows (1200 real, interleaved 4j+g)
#define NG   1200
#define WSEG 409600    // u16 elements per weight segment [1280][320]
#define UPSEG 409600   // u16 per U perm segment [80 T][10 kt][64 lane][8]
// G perm (f16 halves): tt*163840 + nt*16384 + half*8192 + wm*4096 + wn*2048 + (i*4+j)*256 + ln*4 + r
#define GT_H 163840

// ---------------- workspace layout (byte offsets, 16B aligned) ----------------
#define OFF_ABF    0UL           // bf16 [6144][320]            3,932,160
#define OFF_WBF    3932160UL     // bf16 8 x [1280][320]        6,553,600
#define OFF_WCF    10485760UL    // f32  [300][1800] folded fc1 2,160,000
#define OFF_BIAS   12645760UL    // f32  4 x 1200 interleaved      19,200
#define OFF_GF     12664960UL    // f16  perm                  15,728,640
#define OFF_GR     28393600UL    // f16  perm                  15,728,640
#define OFF_HB     44122240UL    // bf16 2 dirs x [128][320]      163,840
#define OFF_ENC    44286080UL    // f32  [128][600]               307,200
#define OFF_VB     44593280UL    // f32  8 x [64][600]          1,228,800
#define OFF_CO     45822080UL    // f32  8 x [64][300]            614,400
#define OFF_ATT    46436480UL    // f32  3 x 48*64                 36,864
#define OFF_PT     46473344UL    // f32  [2400][64] pooled^T      614,400
#define OFF_LG     47087744UL    // f32  64*300                    76,800
#define OFF_UP     47164544UL    // bf16 4 x Uperm              3,276,800
#define OFF_HX     50441344UL    // bf16 2 buf x 2 dir x [128][320]  327,680
#define OFF_BAR    50769024UL    // u32  8 groups x 256B            2,048

__device__ __forceinline__ float sigf(float x) { return 1.0f / (1.0f + expf(-x)); }
__device__ __forceinline__ float fsig(float x) { return 1.0f / (1.0f + __expf(-x)); }
__device__ __forceinline__ float ftanh(float x) { return 1.0f - 2.0f / (__expf(2.0f * x) + 1.0f); }

__device__ __forceinline__ u16 f2bf(float x) {
    union { float f; u32 u; } v; v.f = x;
    u32 r = v.u + 0x7fffu + ((v.u >> 16) & 1u);   // RNE
    return (u16)(r >> 16);
}
__device__ __forceinline__ float bf2f(u16 x) {
    union { u32 u; float f; } v; v.u = ((u32)x) << 16; return v.f;
}

__device__ __forceinline__ void gld_lds16(const u16* g, u16* l) {
    __builtin_amdgcn_global_load_lds(
        (const __attribute__((address_space(1))) unsigned int*)g,
        (__attribute__((address_space(3))) unsigned int*)l, 16, 0, 0);
}

// ---------------- embedding gather -> bf16, K zero-padded ----------------
__global__ __launch_bounds__(256) void gather_bf(const int* __restrict__ x1,
                                                 const int* __restrict__ x2,
                                                 const float* __restrict__ emb,
                                                 u16* __restrict__ abf) {
    int idx = blockIdx.x * 256 + threadIdx.x;
    if (idx >= MR * KP1) return;
    int r = idx / KP1, k = idx % KP1;
    float v = 0.0f;
    if (k < 300) {
        int t = r >> 7, bc = r & 127;
        int tok = (bc < 64) ? x1[t * 64 + bc] : x2[t * 64 + bc - 64];
        v = emb[tok * 300 + k];
    }
    abf[idx] = f2bf(v);
}

// ---------------- 8 weight matrices [1200][300] -> gate-interleaved bf16 [1280][320] ----------------
__global__ __launch_bounds__(256) void wconv8_k(const float* __restrict__ w0, const float* __restrict__ w1,
                                                const float* __restrict__ w2, const float* __restrict__ w3,
                                                const float* __restrict__ w4, const float* __restrict__ w5,
                                                const float* __restrict__ w6, const float* __restrict__ w7,
                                                u16* __restrict__ out) {
    int idx = blockIdx.x * 256 + threadIdx.x;
    if (idx >= 8 * NPG * KP1) return;
    int s = idx / (NPG * KP1), rem = idx % (NPG * KP1);
    int r = rem / KP1, k = rem % KP1;
    const float* w = (s == 0) ? w0 : (s == 1) ? w1 : (s == 2) ? w2 : (s == 3) ? w3
                   : (s == 4) ? w4 : (s == 5) ? w5 : (s == 6) ? w6 : w7;
    float v = 0.0f;
    if (r < NG && k < 300) {
        int j = r >> 2, g = r & 3;
        v = w[(g * 300 + j) * 300 + k];
    }
    out[idx] = f2bf(v);
}

// ---------------- U segs -> B-fragment-major perm: UP[seg][T][kt][lane][8] ----------------
__global__ __launch_bounds__(256) void uperm_k(const u16* __restrict__ WU,
                                               u16* __restrict__ UP) {
    int idx = blockIdx.x * 256 + threadIdx.x;
    if (idx >= 4 * UPSEG) return;
    int seg = idx / UPSEG, pos = idx % UPSEG;
    int T = pos / 5120, kt = (pos / 512) % 10, l = (pos >> 3) & 63, e = pos & 7;
    int n = T * 16 + (l & 15);
    int k = kt * 32 + (l >> 4) * 8 + e;
    UP[idx] = WU[(size_t)seg * WSEG + (size_t)n * KP1 + k];
}

// ---------------- 4 bias pairs -> interleaved f32 [4][1200] ----------------
__global__ __launch_bounds__(256) void bconv_k(const float* __restrict__ b0i, const float* __restrict__ b0h,
                                               const float* __restrict__ b1i, const float* __restrict__ b1h,
                                               const float* __restrict__ b2i, const float* __restrict__ b2h,
                                               const float* __restrict__ b3i, const float* __restrict__ b3h,
                                               float* __restrict__ out) {
    int idx = blockIdx.x * 256 + threadIdx.x;
    if (idx >= 4 * NG) return;
    int s = idx / NG, n = idx % NG;
    int j = n >> 2, g = n & 3;
    int src = g * 300 + j;
    const float* bi = (s == 0) ? b0i : (s == 1) ? b1i : (s == 2) ? b2i : b3i;
    const float* bh = (s == 0) ? b0h : (s == 1) ? b1h : (s == 2) ? b2h : b3h;
    out[idx] = bi[src] + bh[src];
}

// ---------------- folded fc1 weight (fp32) [300][1800] ----------------
__global__ __launch_bounds__(256) void wcat_k(const float* __restrict__ f1w,
                                              float* __restrict__ wc) {
    int idx = blockIdx.x * 256 + threadIdx.x;
    if (idx >= 300 * 1800) return;
    int n = idx / 1800, k = idx % 1800;
    int nk = n * 2400 + k;
    float v;
    if (k < 600)       v = f1w[nk] + f1w[nk + 1800];
    else if (k < 1200) v = f1w[nk] - f1w[nk + 1200];
    else               v = f1w[nk];
    wc[idx] = v;
}

// ---------------- bf16 MFMA GEMM -> G in consumer-fragment-major f16 layout ----------------
__global__ __launch_bounds__(256) void gemm_bt(const u16* __restrict__ A,
                                               const u16* __restrict__ B,
                                               const float* __restrict__ bias,
                                               _Float16* __restrict__ Gh) {
    __shared__ __align__(16) u16 smA[128 * 32];
    __shared__ __align__(16) u16 smB[128 * 32];
    int m0 = blockIdx.x * 128, n0 = blockIdx.y * 128;
    int tid = threadIdx.x, ln = tid & 63;
    int wm = (tid >> 6) & 1, wn = tid >> 7;
    int lrow = ln & 15, lq = ln >> 4;
    f32x4 acc[4][4] = {};
    for (int k0 = 0; k0 < KP1; k0 += 32) {
#pragma unroll
        for (int p = 0; p < 2; p++) {
            int e = (p * 256 + tid) * 8;
            int r = e >> 5, kk = e & 31;
            gld_lds16(A + (size_t)(m0 + r) * KP1 + k0 + kk, smA + e);
            gld_lds16(B + (size_t)(n0 + r) * KP1 + k0 + kk, smB + e);
        }
        __syncthreads();
        bf16x8 av[4], bv[4];
#pragma unroll
        for (int i = 0; i < 4; i++) {
            av[i] = *(const bf16x8*)&smA[(wm * 64 + i * 16 + lrow) * 32 + lq * 8];
            bv[i] = *(const bf16x8*)&smB[(wn * 64 + i * 16 + lrow) * 32 + lq * 8];
        }
#pragma unroll
        for (int i = 0; i < 4; i++)
#pragma unroll
            for (int j = 0; j < 4; j++)
                acc[i][j] = __builtin_amdgcn_mfma_f32_16x16x32_bf16(av[i], bv[j], acc[i][j], 0, 0, 0);
        __syncthreads();
    }
    // perm store: half=wm (this wave's 64-row group), consumer wm = i>>1, i' = i&1
    size_t tb = (size_t)blockIdx.x * GT_H + (size_t)blockIdx.y * 16384
              + (size_t)wm * 8192 + (size_t)wn * 2048 + (size_t)ln * 4;
#pragma unroll
    for (int i = 0; i < 4; i++)
#pragma unroll
        for (int j = 0; j < 4; j++) {
            int n = n0 + wn * 64 + j * 16 + lrow;
            f16x4 v;
            if (n < NG) {
                float bb = bias[n];
#pragma unroll
                for (int r = 0; r < 4; r++) v[r] = (_Float16)(acc[i][j][r] + bb);
            } else {
                v = (f16x4)0;
            }
            *(f16x4*)(Gh + tb + (size_t)(i >> 1) * 4096 + (size_t)(((i & 1) * 4 + j)) * 256) = v;
        }
}

// ---------------- LSTM: gate-split x batch-half-split, sc1 h exchange, relaxed barrier ----------------
// grid (10 nt, 2 dir, 2 half), block 256 = 4 waves (wm = w&1 batch-quarter, wn = w>>1 gate-half).
// U slice (80 KB) LDS-resident fragment-major; h via agent-scope atomics (L2 bypass, no fences).
__global__ __launch_bounds__(256, 1) void lstm_sync(const _Float16* __restrict__ Gf,
                                                    const _Float16* __restrict__ Gr,
                                                    const u16* __restrict__ Upf,
                                                    const u16* __restrict__ Upr,
                                                    u16* __restrict__ hx,
                                                    u16* __restrict__ hb,
                                                    u32* __restrict__ barbase) {
    int nt = blockIdx.x, dir = blockIdx.y, half = blockIdx.z;
    const _Float16* G = dir ? Gr : Gf;
    const u16* Up = dir ? Upr : Upf;
    u32* bar = barbase + (dir * 2 + half) * 64;

    int tid = threadIdx.x, ln = tid & 63, w = tid >> 6;
    int wm = w & 1, wn = w >> 1;
    int lrow = ln & 15, lq = ln >> 4;

    __shared__ __align__(16) u16 Ulds[80 * 512];    // 8 T x 10 kt x 64 x 8  (80 KB)
    __shared__ float P[64][132];                    // gate staging (33 KB)

    // stage this block's U slice (linear copy, fragment-major)
    for (int p = 0; p < 20; p++) {
        int e = (p * 256 + tid) * 8;
        gld_lds16(Up + (size_t)nt * 40960 + e, Ulds + e);
    }
    __syncthreads();

    const u64* HXu = (const u64*)hx;
    u32* HXw = (u32*)hx;
    u32* HOw = (u32*)hb;

    int jp = tid & 15, bg = tid >> 4;
    bool jok = !(nt == 9 && jp >= 6);               // j0 = nt*32 + 2*jp < 300
    float c[4][2];
#pragma unroll
    for (int q = 0; q < 4; q++) { c[q][0] = 0.0f; c[q][1] = 0.0f; }

    const _Float16* Gs = G + (size_t)nt * 16384 + (size_t)half * 8192
                       + (size_t)wm * 4096 + (size_t)wn * 2048 + (size_t)ln * 4;
    f16x4 gpre[8];
    {
        int ttg = dir ? 47 : 0;
        const _Float16* Gt = Gs + (size_t)ttg * GT_H;
#pragma unroll
        for (int f = 0; f < 8; f++) gpre[f] = *(const f16x4*)(Gt + (size_t)f * 256);
    }

    for (int t = 0; t < 48; t++) {
        // ---- load h A-fragments via agent-coherent (sc1) loads: fresh from L3 ----
        union { u64 d[2]; bf16x8 v; } hfrag[2][10];
        const u64* hb0 = HXu + ((size_t)(t & 1) * 2 + dir) * 10240;
#pragma unroll
        for (int i = 0; i < 2; i++) {
            int bcg = half * 64 + wm * 32 + i * 16 + lrow;
            const u64* rp = hb0 + (size_t)bcg * 80 + lq * 2;
#pragma unroll
            for (int kt = 0; kt < 10; kt++) {
                hfrag[i][kt].d[0] = __hip_atomic_load(rp + kt * 8,     __ATOMIC_RELAXED, __HIP_MEMORY_SCOPE_AGENT);
                hfrag[i][kt].d[1] = __hip_atomic_load(rp + kt * 8 + 1, __ATOMIC_RELAXED, __HIP_MEMORY_SCOPE_AGENT);
            }
        }

        f32x4 acc[2][4];
#pragma unroll
        for (int i = 0; i < 2; i++)
#pragma unroll
            for (int j = 0; j < 4; j++) {
                f32x4 a;
#pragma unroll
                for (int r = 0; r < 4; r++) a[r] = (float)gpre[i * 4 + j][r];
                acc[i][j] = a;
            }

#pragma unroll
        for (int kt = 0; kt < 10; kt++) {
            bf16x8 bv[4];
#pragma unroll
            for (int j = 0; j < 4; j++)
                bv[j] = *(const bf16x8*)&Ulds[((size_t)(wn * 4 + j) * 10 + kt) * 512 + ln * 8];
#pragma unroll
            for (int i = 0; i < 2; i++)
#pragma unroll
                for (int j = 0; j < 4; j++)
                    acc[i][j] = __builtin_amdgcn_mfma_f32_16x16x32_bf16(hfrag[i][kt].v, bv[j], acc[i][j], 0, 0, 0);
        }

        // stage gates to LDS
#pragma unroll
        for (int i = 0; i < 2; i++)
#pragma unroll
            for (int j = 0; j < 4; j++) {
                int col = wn * 64 + j * 16 + lrow;
#pragma unroll
                for (int r = 0; r < 4; r++)
                    P[wm * 32 + i * 16 + lq * 4 + r][col] = acc[i][j][r];
            }
        __syncthreads();

        // prefetch next G (coalesced; drained by pre-barrier syncthreads)
        if (t < 47) {
            int ttg = dir ? 46 - t : t + 1;
            const _Float16* Gt = Gs + (size_t)ttg * GT_H;
#pragma unroll
            for (int f = 0; f < 8; f++) gpre[f] = *(const f16x4*)(Gt + (size_t)f * 256);
        }

        // nonlinearity: thread owns (bc = bg*4+q, j = nt*32 + 2*jp + {0,1}); c in regs
        if (jok) {
            u32* hxo = HXw + ((size_t)((t + 1) & 1) * 2 + dir) * 20480;
#pragma unroll
            for (int q = 0; q < 4; q++) {
                int bc = bg * 4 + q;
                f32x4 g0 = *(const f32x4*)&P[bc][8 * jp];
                f32x4 g1 = *(const f32x4*)&P[bc][8 * jp + 4];
                float cn0 = fsig(g0[1]) * c[q][0] + fsig(g0[0]) * ftanh(g0[2]);
                float hn0 = fsig(g0[3]) * ftanh(cn0);
                float cn1 = fsig(g1[1]) * c[q][1] + fsig(g1[0]) * ftanh(g1[2]);
                float hn1 = fsig(g1[3]) * ftanh(cn1);
                c[q][0] = cn0; c[q][1] = cn1;
                u32 pk = (u32)f2bf(hn0) | ((u32)f2bf(hn1) << 16);
                int bcg = half * 64 + bc;
                size_t oi = (size_t)bcg * 160 + nt * 16 + jp;
                if (t < 47)
                    __hip_atomic_store(hxo + oi, pk, __ATOMIC_RELAXED, __HIP_MEMORY_SCOPE_AGENT);
                else
                    HOw[(size_t)dir * 20480 + oi] = pk;
            }
        }

        if (t < 47) {
            __syncthreads();                 // drains each wave's vmcnt(0): h stores acked at L3
            if (tid == 0) {
                __hip_atomic_fetch_add(bar, 1u, __ATOMIC_RELAXED, __HIP_MEMORY_SCOPE_AGENT);
                u32 tgt = 10u * (u32)(t + 1);
                while (__hip_atomic_load(bar, __ATOMIC_RELAXED, __HIP_MEMORY_SCOPE_AGENT) < tgt)
                    __builtin_amdgcn_s_sleep(2);
            }
            __syncthreads();
        } else {
            __syncthreads();                 // P reuse safety for exit
        }
    }
}

// ---------------- final-h concat (batch-reversal quirk): [128][600] f32 ----------------
__global__ __launch_bounds__(256) void enc_k(const u16* __restrict__ hF,
                                             const u16* __restrict__ hR,
                                             float* __restrict__ enc) {
    int idx = blockIdx.x * 256 + threadIdx.x;
    if (idx >= 128 * 600) return;
    int bc = idx / 600, d = idx % 600;
    int seq = bc >> 6, b = bc & 63;
    enc[idx] = (d < 300) ? bf2f(hF[bc * KP1 + d])
                         : bf2f(hR[(seq * 64 + 63 - b) * KP1 + d - 300]);
}

// ---------------- build 8 coefficient vectors V[8][64][600] ----------------
__global__ __launch_bounds__(256) void vbuf_k(const float* __restrict__ enc,
                                              float* __restrict__ V) {
    int idx = blockIdx.x * 256 + threadIdx.x;
    if (idx >= 64 * 600) return;
    int b = idx / 600, d = idx % 600;
    float e1 = enc[b * 600 + d], e2 = enc[(64 + b) * 600 + d];
    float p = fmaxf(e2, 0.0f), nn = fminf(e2, 0.0f);
    V[0 * 38400 + idx] = e1;
    V[1 * 38400 + idx] = p;
    V[2 * 38400 + idx] = nn;
    V[3 * 38400 + idx] = e1 * p;
    V[4 * 38400 + idx] = e1 * nn;
    V[5 * 38400 + idx] = e2;
    V[6 * 38400 + idx] = e1;
    V[7 * 38400 + idx] = e1 * e2;
}

// ---------------- attention scalars (rank-1 collapse): AMX/AMN/SS [48][64] ----------------
__global__ __launch_bounds__(256) void attn_lite(const float* __restrict__ enc,
                                                 const float* __restrict__ x1m,
                                                 const float* __restrict__ x2m,
                                                 float* __restrict__ AMX,
                                                 float* __restrict__ AMN,
                                                 float* __restrict__ SS) {
    int b = blockIdx.x, tid = threadIdx.x;
    __shared__ float sc[48][49];
    __shared__ float rmx[4], rmn[4];
    __shared__ float MxMn[2];
    float mx = -3.4e38f, mn = 3.4e38f;
    for (int d = tid; d < 600; d += 256) {
        float p = enc[b * 600 + d] * enc[(64 + b) * 600 + d];
        mx = fmaxf(mx, p); mn = fminf(mn, p);
    }
    for (int off = 32; off; off >>= 1) {
        mx = fmaxf(mx, __shfl_down(mx, off));
        mn = fminf(mn, __shfl_down(mn, off));
    }
    if ((tid & 63) == 0) { rmx[tid >> 6] = mx; rmn[tid >> 6] = mn; }
    __syncthreads();
    if (tid == 0) {
        MxMn[0] = fmaxf(fmaxf(rmx[0], rmx[1]), fmaxf(rmx[2], rmx[3]));
        MxMn[1] = fminf(fminf(rmn[0], rmn[1]), fminf(rmn[2], rmn[3]));
    }
    __syncthreads();
    float Mx = MxMn[0], Mn = MxMn[1];
    for (int idx = tid; idx < 2304; idx += 256) {
        int i = idx / 48, j = idx % 48;
        float q = x1m[i * 64 + b] * x2m[j * 64 + b];
        sc[i][j] = (q > 0.0f) ? q * Mx : ((q < 0.0f) ? q * Mn : 0.0f);
    }
    __syncthreads();
    if (tid < 48) {
        int i = tid;
        float m = -3.4e38f;
        for (int j = 0; j < 48; j++) m = fmaxf(m, sc[i][j]);
        float sum = 0.0f;
        for (int j = 0; j < 48; j++) sum += expf(sc[i][j] - m) * x2m[j * 64 + b];
        float wmax = -3.4e38f, wmin = 3.4e38f;
        for (int j = 0; j < 48; j++) {
            float w = expf(sc[i][j] - m) * x2m[j * 64 + b] * x2m[j * 64 + b];
            wmax = fmaxf(wmax, w); wmin = fminf(wmin, w);
        }
        AMX[i * 64 + b] = wmax / sum;
        AMN[i * 64 + b] = wmin / sum;
    } else if (tid >= 64 && tid < 112) {
        int j = tid - 64;
        float m = -3.4e38f;
        for (int i = 0; i < 48; i++) m = fmaxf(m, sc[i][j]);
        float sum = 0.0f, sm = 0.0f;
        for (int i = 0; i < 48; i++) {
            float e = expf(sc[i][j] - m) * x1m[i * 64 + b];
            sum += e; sm += e * x1m[i * 64 + b];
        }
        SS[j * 64 + b] = sm / sum;
    }
}

// ---------------- 8 small fp32 GEMMs: CO[s][64][300] = V[s] @ WcSlice^T ----------------
__global__ __launch_bounds__(256) void coeff_gemm(const float* __restrict__ V,
                                                  const float* __restrict__ Wc,
                                                  float* __restrict__ CO) {
    __shared__ float As[16][64];
    __shared__ float Ws[16][64];
    int s = blockIdx.y;
    const int offs[8] = {0, 600, 600, 1200, 1200, 0, 600, 1200};
    int koff = offs[s];
    const float* A = V + (size_t)s * 38400;
    float* C = CO + (size_t)s * 19200;
    int n0 = blockIdx.x * 64;
    int tid = threadIdx.x;
    int lrow = tid >> 2;
    int lk4 = (tid & 3) << 2;
    int tm = (tid & 15) << 2;
    int tn = (tid >> 4) << 2;
    int nW = n0 + lrow;
    float acc[4][4] = {};
    for (int k0 = 0; k0 < 600; k0 += 16) {
        __syncthreads();
#pragma unroll
        for (int q = 0; q < 4; q++) {
            int k = k0 + lk4 + q;
            As[lk4 + q][lrow] = (k < 600) ? A[lrow * 600 + k] : 0.0f;
            Ws[lk4 + q][lrow] = (k < 600 && nW < 300) ? Wc[(size_t)nW * 1800 + koff + k] : 0.0f;
        }
        __syncthreads();
#pragma unroll
        for (int kk = 0; kk < 16; kk++) {
            float a0 = As[kk][tm], a1 = As[kk][tm + 1], a2 = As[kk][tm + 2], a3 = As[kk][tm + 3];
            float w0 = Ws[kk][tn], w1 = Ws[kk][tn + 1], w2 = Ws[kk][tn + 2], w3 = Ws[kk][tn + 3];
            acc[0][0] += a0 * w0; acc[0][1] += a0 * w1; acc[0][2] += a0 * w2; acc[0][3] += a0 * w3;
            acc[1][0] += a1 * w0; acc[1][1] += a1 * w1; acc[1][2] += a1 * w2; acc[1][3] += a1 * w3;
            acc[2][0] += a2 * w0; acc[2][1] += a2 * w1; acc[2][2] += a2 * w2; acc[2][3] += a2 * w3;
            acc[3][0] += a3 * w0; acc[3][1] += a3 * w1; acc[3][2] += a3 * w2; acc[3][3] += a3 * w3;
        }
    }
#pragma unroll
    for (int ii = 0; ii < 4; ii++) {
        int m = tm + ii;
#pragma unroll
        for (int jn = 0; jn < 4; jn++) {
            int n = n0 + tn + jn;
            if (n < 300) C[m * 300 + n] = acc[ii][jn];
        }
    }
}

// ---------------- rank-combine + relu -> bf16 h1 (t-major [6144][320]) ----------------
__global__ __launch_bounds__(320) void combine_k(const float* __restrict__ CO,
                                                 const float* __restrict__ f1b,
                                                 const float* __restrict__ x1m,
                                                 const float* __restrict__ x2m,
                                                 const float* __restrict__ AMX,
                                                 const float* __restrict__ AMN,
                                                 const float* __restrict__ SS,
                                                 u16* __restrict__ OUT) {
    int r = blockIdx.x;
    int t = r >> 7, bc = r & 127;
    int seq = bc >> 6, b = bc & 63;
    int n = threadIdx.x;
    if (n >= 300) return;
    int bn = b * 300 + n;
    float pre;
    if (seq == 0) {
        float m1 = x1m[t * 64 + b], am = AMX[t * 64 + b], an = AMN[t * 64 + b];
        pre = m1 * CO[bn] + am * CO[19200 + bn] + an * CO[2 * 19200 + bn]
            + m1 * am * CO[3 * 19200 + bn] + m1 * an * CO[4 * 19200 + bn] + f1b[n];
    } else {
        float m2 = x2m[t * 64 + b], sv = SS[t * 64 + b];
        pre = m2 * CO[5 * 19200 + bn] + sv * CO[6 * 19200 + bn]
            + m2 * sv * CO[7 * 19200 + bn] + f1b[n];
    }
    OUT[(size_t)r * KP1 + n] = f2bf(fmaxf(pre, 0.0f));
}

// ---------------- masked mean/max pooling -> pooled^T [2400][64] ----------------
__global__ __launch_bounds__(256) void pool_k(const float* __restrict__ dctx,
                                              const float* __restrict__ x1m,
                                              const float* __restrict__ x2m,
                                              float* __restrict__ pooledT) {
    int idx = blockIdx.x * 256 + threadIdx.x;
    if (idx >= 64 * 2400) return;
    int b = idx / 2400, col = idx % 2400;
    int sec = col / 600, d = col % 600;
    const float* msk = (sec < 2) ? x1m : x2m;
    float v = dctx[((sec < 2 ? 0 : 64) + b) * 600 + d];
    float out;
    if ((sec & 1) == 0) {
        float s = 0, sm = 0;
        for (int t = 0; t < 48; t++) { float mv = msk[t * 64 + b]; s += v * mv; sm += mv; }
        out = s / sm;
    } else {
        float m = -3.4e38f;
        for (int t = 0; t < 48; t++) m = fmaxf(m, v * msk[t * 64 + b]);
        out = m;
    }
    pooledT[col * 64 + b] = out;
}

// ---------------- fc2 + tanh ----------------
__global__ __launch_bounds__(256) void fc2_k2(const float* __restrict__ pooledT,
                                              const float* __restrict__ f2w,
                                              const float* __restrict__ f2b,
                                              float* __restrict__ logit) {
    __shared__ float wl[2400];
    __shared__ float red[256];
    int n = blockIdx.x;
    for (int i = threadIdx.x; i < 2400; i += 256) wl[i] = f2w[n * 2400 + i];
    __syncthreads();
    int b = threadIdx.x & 63, kc = threadIdx.x >> 6;
    float acc = 0.0f;
    int k0 = kc * 600;
    for (int kk = 0; kk < 600; kk++) acc += pooledT[(k0 + kk) * 64 + b] * wl[k0 + kk];
    red[threadIdx.x] = acc;
    __syncthreads();
    if (threadIdx.x < 64) {
        float s = red[b] + red[64 + b] + red[128 + b] + red[192 + b];
        logit[b * 300 + n] = tanhf(s + f2b[n]);
    }
}

// ---------------- output layer ----------------
__global__ __launch_bounds__(64) void out_k2(const float* __restrict__ logit,
                                             const float* __restrict__ fow,
                                             const float* __restrict__ fob,
                                             float* __restrict__ out) {
    int b = blockIdx.x, tid = threadIdx.x;
    float p0 = 0, p1 = 0, p2 = 0;
    for (int k = tid; k < 300; k += 64) {
        float l = logit[b * 300 + k];
        p0 += l * fow[k]; p1 += l * fow[300 + k]; p2 += l * fow[600 + k];
    }
    for (int off = 32; off; off >>= 1) {
        p0 += __shfl_down(p0, off);
        p1 += __shfl_down(p1, off);
        p2 += __shfl_down(p2, off);
    }
    if (tid == 0) {
        out[b * 3 + 0] = p0 + fob[0];
        out[b * 3 + 1] = p1 + fob[1];
        out[b * 3 + 2] = p2 + fob[2];
    }
}

extern "C" void kernel_launch(void* const* d_in, const int* in_sizes, int n_in,
                              void* d_out, int out_size, void* d_ws, size_t ws_size,
                              hipStream_t stream) {
    (void)in_sizes; (void)n_in; (void)out_size; (void)ws_size;
    const int*   x1  = (const int*)d_in[0];
    const float* x1m = (const float*)d_in[1];
    const int*   x2  = (const int*)d_in[2];
    const float* x2m = (const float*)d_in[3];
    const float* emb = (const float*)d_in[5];
    const float* eW  = (const float*)d_in[6];
    const float* eU  = (const float*)d_in[7];
    const float* ebi = (const float*)d_in[8];
    const float* ebh = (const float*)d_in[9];
    const float* rW  = (const float*)d_in[10];
    const float* rU  = (const float*)d_in[11];
    const float* rbi = (const float*)d_in[12];
    const float* rbh = (const float*)d_in[13];
    const float* dW  = (const float*)d_in[14];
    const float* dU  = (const float*)d_in[15];
    const float* dbi = (const float*)d_in[16];
    const float* dbh = (const float*)d_in[17];
    const float* sW  = (const float*)d_in[18];
    const float* sU  = (const float*)d_in[19];
    const float* sbi = (const float*)d_in[20];
    const float* sbh = (const float*)d_in[21];
    const float* f1w = (const float*)d_in[22];
    const float* f1b = (const float*)d_in[23];
    const float* f2w = (const float*)d_in[24];
    const float* f2b = (const float*)d_in[25];
    const float* fow = (const float*)d_in[26];
    const float* fob = (const float*)d_in[27];

    char* wsb = (char*)d_ws;
    u16*       ABF  = (u16*)(wsb + OFF_ABF);
    u16*       WBF  = (u16*)(wsb + OFF_WBF);
    float*     WCF  = (float*)(wsb + OFF_WCF);
    float*     BIAS = (float*)(wsb + OFF_BIAS);
    _Float16*  GFh  = (_Float16*)(wsb + OFF_GF);
    _Float16*  GRh  = (_Float16*)(wsb + OFF_GR);
    u16*       HB   = (u16*)(wsb + OFF_HB);
    float*     ENC  = (float*)(wsb + OFF_ENC);
    float*     VB   = (float*)(wsb + OFF_VB);
    float*     CO   = (float*)(wsb + OFF_CO);
    float*     AMX  = (float*)(wsb + OFF_ATT);
    float*     AMN  = AMX + 3072;
    float*     SS   = AMX + 6144;
    float*     PT   = (float*)(wsb + OFF_PT);
    float*     LG   = (float*)(wsb + OFF_LG);
    u16*       UP   = (u16*)(wsb + OFF_UP);
    u16*       HX   = (u16*)(wsb + OFF_HX);
    u32*       BAR  = (u32*)(wsb + OFF_BAR);

    u16* HF0 = HB;
    u16* HR0 = HB + 40960;

    // ---- conversions ----
    gather_bf<<<dim3((MR * KP1 + 255) / 256), 256, 0, stream>>>(x1, x2, emb, ABF);
    wconv8_k<<<dim3((8 * NPG * KP1 + 255) / 256), 256, 0, stream>>>(eW, rW, dW, sW, eU, rU, dU, sU, WBF);
    uperm_k<<<dim3((4 * UPSEG + 255) / 256), 256, 0, stream>>>(WBF + 4 * WSEG, UP);
    bconv_k<<<dim3((4 * NG + 255) / 256), 256, 0, stream>>>(ebi, ebh, rbi, rbh, dbi, dbh, sbi, sbh, BIAS);
    wcat_k<<<dim3((300 * 1800 + 255) / 256), 256, 0, stream>>>(f1w, WCF);
    hipMemsetAsync(wsb + OFF_BAR, 0, 2048, stream);

    // ---- encoder ----
    hipMemsetAsync(wsb + OFF_HX, 0, 327680, stream);
    gemm_bt<<<dim3(48, 10), 256, 0, stream>>>(ABF, WBF,        BIAS,      GFh);
    gemm_bt<<<dim3(48, 10), 256, 0, stream>>>(ABF, WBF + WSEG, BIAS + NG, GRh);
    lstm_sync<<<dim3(10, 2, 2), 256, 0, stream>>>(GFh, GRh, UP, UP + UPSEG, HX, HB, BAR);

    // ---- attention (rank-1 collapse) + fc1 ----
    enc_k<<<dim3((128 * 600 + 255) / 256), 256, 0, stream>>>(HF0, HR0, ENC);
    vbuf_k<<<dim3((64 * 600 + 255) / 256), 256, 0, stream>>>(ENC, VB);
    attn_lite<<<dim3(64), 256, 0, stream>>>(ENC, x1m, x2m, AMX, AMN, SS);
    coeff_gemm<<<dim3(5, 8), 256, 0, stream>>>(VB, WCF, CO);
    combine_k<<<dim3(6144), 320, 0, stream>>>(CO, f1b, x1m, x2m, AMX, AMN, SS, ABF);

    // ---- decoder ----
    hipMemsetAsync(wsb + OFF_HX, 0, 327680, stream);
    gemm_bt<<<dim3(48, 10), 256, 0, stream>>>(ABF, WBF + 2 * WSEG, BIAS + 2 * NG, GFh);
    gemm_bt<<<dim3(48, 10), 256, 0, stream>>>(ABF, WBF + 3 * WSEG, BIAS + 3 * NG, GRh);
    lstm_sync<<<dim3(10, 2, 2), 256, 0, stream>>>(GFh, GRh, UP + 2 * UPSEG, UP + 3 * UPSEG, HX, HB, BAR + 1024);

    // ---- pooling + classifier ----
    enc_k<<<dim3((128 * 600 + 255) / 256), 256, 0, stream>>>(HF0, HR0, ENC);
    pool_k<<<dim3((64 * 2400 + 255) / 256), 256, 0, stream>>>(ENC, x1m, x2m, PT);
    fc2_k2<<<dim3(300), 256, 0, stream>>>(PT, f2w, f2b, LG);
    out_k2<<<dim3(64), 64, 0, stream>>>(LG, fow, fob, (float*)d_out);
}